// Round 12
// baseline (79.387 us; speedup 1.0000x reference)
//
#include <hip/hip_runtime.h>
#include <math.h>

#define BB 256
#define NN 1024
#define DD 128
#define NCHUNK 4
#define ROWS (NN / NCHUNK)   // 256

// workspace layout (in floats)
#define PA_OFF   0
#define PCI_OFF  (NCHUNK*BB*DD)            // 131072
#define PCJ_OFF  (2*NCHUNK*BB*DD)          // 262144
#define PCNT_OFF (3*NCHUNK*BB*DD)          // 393216
#define U_OFF    (PCNT_OFF + NCHUNK*BB)    // 394240
#define V_OFF    (U_OFF + BB*DD)           // 427008
// total = 459776 floats = 1.84 MB

// ---------------------------------------------------------------------------
// Kernel 1 (v5): SPARSE masked streaming reductions, one array per block.
//   role 0: P_A  = sum_n (mi-mj)*d ; role 1: P_Ci = sum_n mi*si ;
//   role 2: P_Cj = sum_n mj*sj. Zero-weight rows never loaded.
// v5: (weight,idx) packed in one float2 LDS read; 8 float4 loads in flight;
// next iw-batch prefetched before consuming current (breaks LDS->VMEM chain).
// grid = (NCHUNK, BB, 3), block = 256 (32 lanes x 8 row-groups).
// ---------------------------------------------------------------------------
__global__ __launch_bounds__(256) void k1_sparse(
    const float* __restrict__ d, const float* __restrict__ si,
    const float* __restrict__ sj, const void* __restrict__ miv,
    const void* __restrict__ mjv, float* __restrict__ ws)
{
    const int chunk = blockIdx.x;
    const int b     = blockIdx.y;
    const int role  = blockIdx.z;
    const int t     = threadIdx.x;
    const int lane  = t & 31;   // float4 column group: cols lane*4 .. +3
    const int rg    = t >> 5;   // row group 0..7
    const int wid   = t >> 6;   // wave 0..3
    const int l64   = t & 63;

    // ---- mask dtype auto-detect (bool bytes vs int32) ----
    __shared__ int s_mode;
    if (t == 0) s_mode = 0;
    __syncthreads();
    {
        const unsigned int* a = (const unsigned int*)miv;
        const unsigned int* c = (const unsigned int*)mjv;
        if ((a[t] | c[t]) > 1u) s_mode = 1;  // bytes of 0/1 packed in a word
    }
    __syncthreads();
    const bool bytes_mode = (s_mode != 0);

    // ---- stage weights, compute cnt (role 0), compact nonzero rows ----
    __shared__ float2 s_iw[ROWS];    // (weight, idx-as-float) compacted
    __shared__ int    s_wcnt[4];     // per-wave keep counts
    __shared__ int    s_woff[5];     // exclusive scan + total
    __shared__ int    s_cnt4[4];     // per-wave (sum mi - sum mj)

    const int    n0      = chunk * ROWS;
    const size_t rowbase = (size_t)b * NN;

    float w;
    {
        const size_t m = rowbase + (size_t)(n0 + t);
        float fi, fj;
        if (bytes_mode) {
            fi = (float)((const unsigned char*)miv)[m];
            fj = (float)((const unsigned char*)mjv)[m];
        } else {
            fi = (float)((const int*)miv)[m];
            fj = (float)((const int*)mjv)[m];
        }
        w = (role == 0) ? (fi - fj) : ((role == 1) ? fi : fj);
        if (role == 0) {
            const unsigned long long bi = __ballot(fi != 0.f);
            const unsigned long long bj = __ballot(fj != 0.f);
            if (l64 == 0) s_cnt4[wid] = __popcll(bi) - __popcll(bj);
        }
    }
    const bool keep = (w != 0.f);
    const unsigned long long ball = __ballot(keep);
    const int prefix = __popcll(ball & ((1ull << l64) - 1ull));
    if (l64 == 0) s_wcnt[wid] = __popcll(ball);
    __syncthreads();
    if (t == 0) {
        int a0 = 0;
        #pragma unroll
        for (int ww = 0; ww < 4; ++ww) { s_woff[ww] = a0; a0 += s_wcnt[ww]; }
        s_woff[4] = a0;
        if (role == 0)
            ws[PCNT_OFF + chunk * BB + b] =
                (float)(s_cnt4[0] + s_cnt4[1] + s_cnt4[2] + s_cnt4[3]);
    }
    __syncthreads();
    const int K    = s_woff[4];
    const int Kpad = (K + 63) & ~63;   // batch granularity 64 rows
    if (keep) {
        const int pos = s_woff[wid] + prefix;
        s_iw[pos] = make_float2(w, __int_as_float(t));
    }
    for (int p = K + t; p < ROWS; p += 256)   // zero-fill full table
        s_iw[p] = make_float2(0.f, __int_as_float(0));
    __syncthreads();

    const float* src = (role == 0) ? d : ((role == 1) ? si : sj);
    const size_t cbase = (rowbase + (size_t)n0) * (size_t)DD
                       + (size_t)lane * 4;

    float acc[4] = {0.f, 0.f, 0.f, 0.f};

    float2 iw[8];
    #pragma unroll
    for (int u = 0; u < 8; ++u) iw[u] = s_iw[u * 8 + rg];

    for (int i = 0; i < Kpad; i += 64) {
        // 8 independent 512B-row gathers in flight
        float4 v[8];
        #pragma unroll
        for (int u = 0; u < 8; ++u) {
            const int r = __float_as_int(iw[u].y);
            v[u] = *(const float4*)(src + cbase + (size_t)r * DD);
        }
        // prefetch next iw batch while loads are in flight (s_iw fully
        // initialized to 256 entries, so reads are always in-bounds)
        float2 iw2[8];
        const int ib = i + 64;
        if (ib < Kpad) {
            #pragma unroll
            for (int u = 0; u < 8; ++u) iw2[u] = s_iw[ib + u * 8 + rg];
        } else {
            #pragma unroll
            for (int u = 0; u < 8; ++u) iw2[u] = make_float2(0.f, 0.f);
        }
        #pragma unroll
        for (int u = 0; u < 8; ++u) {
            acc[0] = fmaf(iw[u].x, v[u].x, acc[0]);
            acc[1] = fmaf(iw[u].x, v[u].y, acc[1]);
            acc[2] = fmaf(iw[u].x, v[u].z, acc[2]);
            acc[3] = fmaf(iw[u].x, v[u].w, acc[3]);
        }
        #pragma unroll
        for (int u = 0; u < 8; ++u) iw[u] = iw2[u];
    }

    // ---- reduce the 8 row-groups (t strides of 32); [5] breaks bank stride
    __shared__ float red[256][5];
    #pragma unroll
    for (int i = 0; i < 4; ++i) red[t][i] = acc[i];
    __syncthreads();
    if (t < 128) {
        #pragma unroll
        for (int i = 0; i < 4; ++i) red[t][i] += red[t + 128][i];
    }
    __syncthreads();
    if (t < 64) {
        #pragma unroll
        for (int i = 0; i < 4; ++i) red[t][i] += red[t + 64][i];
    }
    __syncthreads();
    if (t < 32) {
        #pragma unroll
        for (int i = 0; i < 4; ++i) red[t][i] += red[t + 32][i];
        const size_t poff = ((role == 0) ? PA_OFF : ((role == 1) ? PCI_OFF
                                                                 : PCJ_OFF))
                          + ((size_t)chunk * BB + b) * DD;
        float* P = ws + poff;
        #pragma unroll
        for (int i = 0; i < 4; ++i) P[t * 4 + i] = red[t][i];
    }
}

// ---------------------------------------------------------------------------
// Kernel 2 (v4): u/v[b][p] = sum_c relu(dm[b]·W1[:,p*128+c] + b1) * w2{a,b}[c]
// LDS pipe starved; W1 read from global exactly once per (qb,bg) pair:
//   - grid 256 = (16 qb x 16 bg); blockIdx = bg*16+qb so all 16 bg-blocks of
//     a qb share an XCD (%8 = qb%8) -> W1 slice (2MB/XCD) stays L2-resident
//   - block 512 thr: q = qb*1024 + (t&255)*4 (4 q/thread, coalesced float4);
//     b-tile 16, wave-uniform halves bb0 = (t>>8)*8 (8 b/thread)
//   - dm tile in 8KB LDS dmsT[k][16]; a-reads = 2 UNIFORM ds_read_b128/k
//   - W1 global->reg + A LDS->reg, 8-k-deep named double buffer
// Per k per wave: 32 FMA (128 VALU cyc) vs ~10 LDS cyc + 1KB coalesced L2.
// ---------------------------------------------------------------------------
__global__ __launch_bounds__(512, 2) void k2_gemm(
    const float* __restrict__ d, const float* __restrict__ W1,
    const float* __restrict__ b1, const float* __restrict__ W2,
    float* __restrict__ ws)
{
    const int qb  = blockIdx.x & 15;
    const int bg  = blockIdx.x >> 4;
    const int t   = threadIdx.x;
    const int q0  = qb * 1024 + (t & 255) * 4;
    const int b0  = bg * 16;
    const int bb0 = (t >> 8) * 8;     // 0 or 8 (wave-uniform)

    __shared__ float dmsT[128][16];   // [k][bb] 8 KB

    // stage dm transposed: 512 float4 loads (coalesced over k per b-row)
    {
        const int bb = t & 15;
        const int k4 = (t >> 4) * 4;  // 0..124
        const float4 v = *(const float4*)(d + (size_t)(b0 + bb) * (NN * DD) + k4);
        dmsT[k4 + 0][bb] = v.x;
        dmsT[k4 + 1][bb] = v.y;
        dmsT[k4 + 2][bb] = v.z;
        dmsT[k4 + 3][bb] = v.w;
    }
    __syncthreads();

    const float* w1p = W1 + q0;

#define LDA(A, kk)                                                            \
    {                                                                         \
        _Pragma("unroll")                                                     \
        for (int c = 0; c < 4; ++c) {                                         \
            A[2*c]   = *(const float4*)&dmsT[(kk) + c][bb0];                  \
            A[2*c+1] = *(const float4*)&dmsT[(kk) + c][bb0 + 4];              \
        }                                                                     \
    }
#define LDW(Wb, kk)                                                           \
    {                                                                         \
        _Pragma("unroll")                                                     \
        for (int c = 0; c < 4; ++c)                                           \
            Wb[c] = *(const float4*)(w1p + (size_t)((kk) + c) * 16384);       \
    }
#define FMA4(A, Wb)                                                           \
    {                                                                         \
        _Pragma("unroll")                                                     \
        for (int c = 0; c < 4; ++c) {                                         \
            const float aq[8] = {A[2*c].x,   A[2*c].y,   A[2*c].z,   A[2*c].w,\
                                 A[2*c+1].x, A[2*c+1].y, A[2*c+1].z, A[2*c+1].w};\
            const float wq[4] = {Wb[c].x, Wb[c].y, Wb[c].z, Wb[c].w};         \
            _Pragma("unroll")                                                 \
            for (int i = 0; i < 8; ++i) {                                     \
                _Pragma("unroll")                                             \
                for (int j = 0; j < 4; ++j)                                   \
                    acc[i][j] = fmaf(aq[i], wq[j], acc[i][j]);                \
            }                                                                 \
        }                                                                     \
    }

    float acc[8][4];
    #pragma unroll
    for (int i = 0; i < 8; ++i) {
        #pragma unroll
        for (int j = 0; j < 4; ++j) acc[i][j] = 0.f;
    }

    float4 A0[8], A1[8], Wv0[4], Wv1[4];
    LDA(A0, 0);
    LDW(Wv0, 0);
    for (int k0 = 0; k0 < 128; k0 += 8) {
        LDA(A1, k0 + 4);
        LDW(Wv1, k0 + 4);
        FMA4(A0, Wv0);
        const int k8 = (k0 + 8 < 128) ? (k0 + 8) : 0;  // tail: dummy reload
        LDA(A0, k8);
        LDW(Wv0, k8);
        FMA4(A1, Wv1);
    }
#undef LDA
#undef LDW
#undef FMA4

    // epilogue: bias + relu + w2 contraction over this thread's 4 q's
    const float4 bl  = *(const float4*)(b1 + q0);
    const int    c0  = (t & 31) * 4;          // c = q0 & 127
    const float4 wa4 = *(const float4*)(W2 + c0);
    const float4 wb4 = *(const float4*)(W2 + 128 + c0);
    const float bias[4] = {bl.x, bl.y, bl.z, bl.w};
    const float wa[4]   = {wa4.x, wa4.y, wa4.z, wa4.w};
    const float wv[4]   = {wb4.x, wb4.y, wb4.z, wb4.w};

    float ua[8], va[8];
    #pragma unroll
    for (int i = 0; i < 8; ++i) { ua[i] = 0.f; va[i] = 0.f; }
    #pragma unroll
    for (int j = 0; j < 4; ++j) {
        #pragma unroll
        for (int i = 0; i < 8; ++i) {
            const float g = fmaxf(acc[i][j] + bias[j], 0.f);
            ua[i] = fmaf(g, wa[j], ua[i]);
            va[i] = fmaf(g, wv[j], va[i]);
        }
    }

    // reduce across the 32 lanes of each c-group (covers all 128 c of one p)
    #pragma unroll
    for (int off = 16; off > 0; off >>= 1) {
        #pragma unroll
        for (int i = 0; i < 8; ++i) {
            ua[i] += __shfl_down(ua[i], off, 32);
            va[i] += __shfl_down(va[i], off, 32);
        }
    }
    if ((t & 31) == 0) {
        const int p = qb * 8 + ((t & 255) >> 5);  // output row of M (0..127)
        #pragma unroll
        for (int i = 0; i < 8; ++i) {
            ws[U_OFF + (size_t)(b0 + bb0 + i) * DD + p] = ua[i];
            ws[V_OFF + (size_t)(b0 + bb0 + i) * DD + p] = va[i];
        }
    }
}

// ---------------------------------------------------------------------------
// Kernel 3: per-batch score assembly + sigmoid.
//   out[b] = sigmoid( Adiff·u + (Ci-Cj)·v + b2*cntdiff )
// grid = 256, block = 64 (one wave per batch).
// ---------------------------------------------------------------------------
__global__ __launch_bounds__(64) void k3_final(
    const float* __restrict__ ws, const float* __restrict__ b2p,
    float* __restrict__ out)
{
    const int b = blockIdx.x;
    const int l = threadIdx.x;

    float s = 0.f;
    #pragma unroll
    for (int rep = 0; rep < 2; ++rep) {
        const int k = l + rep * 64;
        float A = 0.f, Ci = 0.f, Cj = 0.f;
        #pragma unroll
        for (int c = 0; c < NCHUNK; ++c) {
            A  += ws[PA_OFF  + ((size_t)c * BB + b) * DD + k];
            Ci += ws[PCI_OFF + ((size_t)c * BB + b) * DD + k];
            Cj += ws[PCJ_OFF + ((size_t)c * BB + b) * DD + k];
        }
        s += A * ws[U_OFF + (size_t)b * DD + k]
           + (Ci - Cj) * ws[V_OFF + (size_t)b * DD + k];
    }
    #pragma unroll
    for (int off = 32; off > 0; off >>= 1) s += __shfl_down(s, off, 64);

    if (l == 0) {
        float cnt = 0.f;
        #pragma unroll
        for (int c = 0; c < NCHUNK; ++c) cnt += ws[PCNT_OFF + c * BB + b];
        const float score = s + b2p[0] * cnt;   // SCALING_FACTOR == 1.0
        out[b] = 1.f / (1.f + expf(-score));
    }
}

extern "C" void kernel_launch(void* const* d_in, const int* in_sizes, int n_in,
                              void* d_out, int out_size, void* d_ws, size_t ws_size,
                              hipStream_t stream)
{
    const float* d   = (const float*)d_in[0];
    const float* si  = (const float*)d_in[1];
    const float* sj  = (const float*)d_in[2];
    const void*  mi  = d_in[3];
    const void*  mj  = d_in[4];
    const float* W1  = (const float*)d_in[5];
    const float* b1  = (const float*)d_in[6];
    const float* W2  = (const float*)d_in[7];
    const float* b2  = (const float*)d_in[8];
    float* ws  = (float*)d_ws;
    float* out = (float*)d_out;

    dim3 g1(NCHUNK, BB, 3);
    k1_sparse<<<g1, 256, 0, stream>>>(d, si, sj, mi, mj, ws);
    k2_gemm<<<256, 512, 0, stream>>>(d, W1, b1, W2, ws);
    k3_final<<<BB, 64, 0, stream>>>(ws, b2, out);
}

// Round 13
// 67.121 us; speedup vs baseline: 1.1827x; 1.1827x over previous
//
#include <hip/hip_runtime.h>
#include <math.h>

#define BB 256
#define NN 1024
#define DD 128
#define NCHUNK 4
#define ROWS (NN / NCHUNK)   // 256

// workspace layout (in floats)
#define PA_OFF   0
#define PCI_OFF  (NCHUNK*BB*DD)            // 131072
#define PCJ_OFF  (2*NCHUNK*BB*DD)          // 262144
#define PCNT_OFF (3*NCHUNK*BB*DD)          // 393216
#define U_OFF    (PCNT_OFF + NCHUNK*BB)    // 394240
#define V_OFF    (U_OFF + BB*DD)           // 427008
// total = 459776 floats = 1.84 MB

// ---------------------------------------------------------------------------
// Fused kernel: 3584 blocks = 3072 k1-role + 512 k2-role, interleaved 6:1
// (idx%7==3 -> k2). k1 is memory-bound (VALUBusy ~4%); k2 is ~537M FMA of
// pure VALU+LDS work on INDEPENDENT inputs -> rides under k1's memory time.
//
// k1 role (r9-exact body): sparse masked streaming reductions.
//   role 0: P_A = sum_n (mi-mj)*d ; 1: P_Ci = sum_n mi*si ; 2: P_Cj = mj*sj
// k2 role: u/v[b][p] = sum_c relu(dm[b]·W1[:,p*128+c] + b1[p*128+c])*w2{a,b}[c]
//   512 blocks = 32 qb (512 q each) x 16 bg (16 b each); thread: 2q x 16b.
//   dm tile in 8KB LDS, a-reads = 4 UNIFORM ds_read_b128/k (broadcast);
//   W1 float2 coalesced global->reg, one 4k-group prefetch ahead.
// ---------------------------------------------------------------------------
__global__ __launch_bounds__(256) void fused_k12(
    const float* __restrict__ d, const float* __restrict__ si,
    const float* __restrict__ sj, const void* __restrict__ miv,
    const void* __restrict__ mjv, const float* __restrict__ W1,
    const float* __restrict__ b1, const float* __restrict__ W2,
    float* __restrict__ ws)
{
    const int idx = blockIdx.x;
    const int t   = threadIdx.x;

    if (idx % 7 == 3) {
        // =================== k2 role ===================
        const int k2id = idx / 7;        // 0..511
        const int qb   = k2id & 31;      // q-superblock of 512
        const int bg   = k2id >> 5;      // 0..15, b-tile of 16
        const int q0   = qb * 512 + t * 2;
        const int b0   = bg * 16;

        __shared__ float dmsT[128][16];  // [k][bb] 8 KB

        for (int s = t; s < 16 * 32; s += 256) {
            const int bb = s & 15;
            const int k4 = (s >> 4) * 4;
            const float4 v =
                *(const float4*)(d + (size_t)(b0 + bb) * (NN * DD) + k4);
            dmsT[k4 + 0][bb] = v.x;
            dmsT[k4 + 1][bb] = v.y;
            dmsT[k4 + 2][bb] = v.z;
            dmsT[k4 + 3][bb] = v.w;
        }
        __syncthreads();

        const float* w1p = W1 + q0;

        float acc[16][2];
        #pragma unroll
        for (int i = 0; i < 16; ++i) { acc[i][0] = 0.f; acc[i][1] = 0.f; }

        float2 Wc[4], Wn[4];
        #pragma unroll
        for (int c = 0; c < 4; ++c)
            Wc[c] = *(const float2*)(w1p + (size_t)c * 16384);

        for (int k0 = 0; k0 < 128; k0 += 4) {
            const int kn = (k0 + 4 < 128) ? (k0 + 4) : 0;  // tail: dummy
            #pragma unroll
            for (int c = 0; c < 4; ++c)
                Wn[c] = *(const float2*)(w1p + (size_t)(kn + c) * 16384);
            #pragma unroll
            for (int c = 0; c < 4; ++c) {
                const int k = k0 + c;
                const float4 a0 = *(const float4*)&dmsT[k][0];
                const float4 a1 = *(const float4*)&dmsT[k][4];
                const float4 a2 = *(const float4*)&dmsT[k][8];
                const float4 a3 = *(const float4*)&dmsT[k][12];
                const float aq[16] = {a0.x, a0.y, a0.z, a0.w,
                                      a1.x, a1.y, a1.z, a1.w,
                                      a2.x, a2.y, a2.z, a2.w,
                                      a3.x, a3.y, a3.z, a3.w};
                const float w0 = Wc[c].x, w1v = Wc[c].y;
                #pragma unroll
                for (int i = 0; i < 16; ++i) {
                    acc[i][0] = fmaf(aq[i], w0,  acc[i][0]);
                    acc[i][1] = fmaf(aq[i], w1v, acc[i][1]);
                }
            }
            #pragma unroll
            for (int c = 0; c < 4; ++c) Wc[c] = Wn[c];
        }

        // epilogue: bias + relu + w2 contraction over this thread's 2 q's
        const float2 bl  = *(const float2*)(b1 + q0);
        const int    c0  = (t & 63) * 2;       // c = q0 & 127
        const float2 wa2 = *(const float2*)(W2 + c0);
        const float2 wb2 = *(const float2*)(W2 + 128 + c0);
        const float bias[2] = {bl.x, bl.y};
        const float wa[2]   = {wa2.x, wa2.y};
        const float wv[2]   = {wb2.x, wb2.y};

        float ua[16], va[16];
        #pragma unroll
        for (int i = 0; i < 16; ++i) { ua[i] = 0.f; va[i] = 0.f; }
        #pragma unroll
        for (int j = 0; j < 2; ++j) {
            #pragma unroll
            for (int i = 0; i < 16; ++i) {
                const float g = fmaxf(acc[i][j] + bias[j], 0.f);
                ua[i] = fmaf(g, wa[j], ua[i]);
                va[i] = fmaf(g, wv[j], va[i]);
            }
        }

        // reduce across the 64 lanes of the wave (all 128 c of one p)
        #pragma unroll
        for (int off = 32; off > 0; off >>= 1) {
            #pragma unroll
            for (int i = 0; i < 16; ++i) {
                ua[i] += __shfl_down(ua[i], off, 64);
                va[i] += __shfl_down(va[i], off, 64);
            }
        }
        if ((t & 63) == 0) {
            const int p = qb * 4 + (t >> 6);   // output row of M (0..127)
            #pragma unroll
            for (int i = 0; i < 16; ++i) {
                ws[U_OFF + (size_t)(b0 + i) * DD + p] = ua[i];
                ws[V_OFF + (size_t)(b0 + i) * DD + p] = va[i];
            }
        }
        return;
    }

    // =================== k1 role (r9-exact body) ===================
    const int k1id  = idx - (idx + 3) / 7;   // 0..3071
    const int chunk = k1id & 3;
    const int b     = (k1id >> 2) & 255;
    const int role  = k1id >> 10;
    const int lane  = t & 31;   // float4 column group: cols lane*4 .. +3
    const int rg    = t >> 5;   // row group 0..7
    const int wid   = t >> 6;   // wave 0..3
    const int l64   = t & 63;

    // ---- mask dtype auto-detect (bool bytes vs int32) ----
    __shared__ int s_mode;
    if (t == 0) s_mode = 0;
    __syncthreads();
    {
        const unsigned int* a = (const unsigned int*)miv;
        const unsigned int* c = (const unsigned int*)mjv;
        if ((a[t] | c[t]) > 1u) s_mode = 1;  // bytes of 0/1 packed in a word
    }
    __syncthreads();
    const bool bytes_mode = (s_mode != 0);

    // ---- stage weights, compute cnt (role 0), compact nonzero rows ----
    __shared__ float s_wc[ROWS];     // compacted weights
    __shared__ short s_idx[ROWS];    // compacted row indices (0..255)
    __shared__ int   s_wcnt[4];      // per-wave keep counts
    __shared__ int   s_woff[5];      // exclusive scan + total
    __shared__ int   s_cnt4[4];      // per-wave (sum mi - sum mj)

    const int    n0      = chunk * ROWS;
    const size_t rowbase = (size_t)b * NN;

    float w;
    {
        const size_t m = rowbase + (size_t)(n0 + t);
        float fi, fj;
        if (bytes_mode) {
            fi = (float)((const unsigned char*)miv)[m];
            fj = (float)((const unsigned char*)mjv)[m];
        } else {
            fi = (float)((const int*)miv)[m];
            fj = (float)((const int*)mjv)[m];
        }
        w = (role == 0) ? (fi - fj) : ((role == 1) ? fi : fj);
        if (role == 0) {
            const unsigned long long bi = __ballot(fi != 0.f);
            const unsigned long long bj = __ballot(fj != 0.f);
            if (l64 == 0) s_cnt4[wid] = __popcll(bi) - __popcll(bj);
        }
    }
    const bool keep = (w != 0.f);
    const unsigned long long ball = __ballot(keep);
    const int prefix = __popcll(ball & ((1ull << l64) - 1ull));
    if (l64 == 0) s_wcnt[wid] = __popcll(ball);
    __syncthreads();
    if (t == 0) {
        int a0 = 0;
        #pragma unroll
        for (int ww = 0; ww < 4; ++ww) { s_woff[ww] = a0; a0 += s_wcnt[ww]; }
        s_woff[4] = a0;
        if (role == 0)
            ws[PCNT_OFF + chunk * BB + b] =
                (float)(s_cnt4[0] + s_cnt4[1] + s_cnt4[2] + s_cnt4[3]);
    }
    __syncthreads();
    const int K    = s_woff[4];
    const int Kpad = (K + 31) & ~31;
    if (keep) {
        const int pos = s_woff[wid] + prefix;
        s_idx[pos] = (short)t;
        s_wc[pos]  = w;
    }
    for (int p = K + t; p < Kpad; p += 256) { s_idx[p] = 0; s_wc[p] = 0.f; }
    __syncthreads();

    const float* src = (role == 0) ? d : ((role == 1) ? si : sj);
    const size_t cbase = (rowbase + (size_t)n0) * (size_t)DD
                       + (size_t)lane * 4;

    float acc[4] = {0.f, 0.f, 0.f, 0.f};

    for (int i = 0; i < Kpad; i += 32) {
        int   r[4];
        float wv[4];
        #pragma unroll
        for (int u = 0; u < 4; ++u) {
            const int p = i + u * 8 + rg;
            r[u]  = s_idx[p];      // broadcast within row-group
            wv[u] = s_wc[p];
        }
        float4 v[4];
        #pragma unroll
        for (int u = 0; u < 4; ++u)
            v[u] = *(const float4*)(src + cbase + (size_t)r[u] * DD);
        #pragma unroll
        for (int u = 0; u < 4; ++u) {
            acc[0] = fmaf(wv[u], v[u].x, acc[0]);
            acc[1] = fmaf(wv[u], v[u].y, acc[1]);
            acc[2] = fmaf(wv[u], v[u].z, acc[2]);
            acc[3] = fmaf(wv[u], v[u].w, acc[3]);
        }
    }

    // ---- reduce the 8 row-groups (t strides of 32); [5] breaks bank stride
    __shared__ float red[256][5];
    #pragma unroll
    for (int i = 0; i < 4; ++i) red[t][i] = acc[i];
    __syncthreads();
    if (t < 128) {
        #pragma unroll
        for (int i = 0; i < 4; ++i) red[t][i] += red[t + 128][i];
    }
    __syncthreads();
    if (t < 64) {
        #pragma unroll
        for (int i = 0; i < 4; ++i) red[t][i] += red[t + 64][i];
    }
    __syncthreads();
    if (t < 32) {
        #pragma unroll
        for (int i = 0; i < 4; ++i) red[t][i] += red[t + 32][i];
        const size_t poff = ((role == 0) ? PA_OFF : ((role == 1) ? PCI_OFF
                                                                 : PCJ_OFF))
                          + ((size_t)chunk * BB + b) * DD;
        float* P = ws + poff;
        #pragma unroll
        for (int i = 0; i < 4; ++i) P[t * 4 + i] = red[t][i];
    }
}

// ---------------------------------------------------------------------------
// Kernel 3: per-batch score assembly + sigmoid.
//   out[b] = sigmoid( Adiff·u + (Ci-Cj)·v + b2*cntdiff )
// grid = 256, block = 64 (one wave per batch).
// ---------------------------------------------------------------------------
__global__ __launch_bounds__(64) void k3_final(
    const float* __restrict__ ws, const float* __restrict__ b2p,
    float* __restrict__ out)
{
    const int b = blockIdx.x;
    const int l = threadIdx.x;

    float s = 0.f;
    #pragma unroll
    for (int rep = 0; rep < 2; ++rep) {
        const int k = l + rep * 64;
        float A = 0.f, Ci = 0.f, Cj = 0.f;
        #pragma unroll
        for (int c = 0; c < NCHUNK; ++c) {
            A  += ws[PA_OFF  + ((size_t)c * BB + b) * DD + k];
            Ci += ws[PCI_OFF + ((size_t)c * BB + b) * DD + k];
            Cj += ws[PCJ_OFF + ((size_t)c * BB + b) * DD + k];
        }
        s += A * ws[U_OFF + (size_t)b * DD + k]
           + (Ci - Cj) * ws[V_OFF + (size_t)b * DD + k];
    }
    #pragma unroll
    for (int off = 32; off > 0; off >>= 1) s += __shfl_down(s, off, 64);

    if (l == 0) {
        float cnt = 0.f;
        #pragma unroll
        for (int c = 0; c < NCHUNK; ++c) cnt += ws[PCNT_OFF + c * BB + b];
        const float score = s + b2p[0] * cnt;   // SCALING_FACTOR == 1.0
        out[b] = 1.f / (1.f + expf(-score));
    }
}

extern "C" void kernel_launch(void* const* d_in, const int* in_sizes, int n_in,
                              void* d_out, int out_size, void* d_ws, size_t ws_size,
                              hipStream_t stream)
{
    const float* d   = (const float*)d_in[0];
    const float* si  = (const float*)d_in[1];
    const float* sj  = (const float*)d_in[2];
    const void*  mi  = d_in[3];
    const void*  mj  = d_in[4];
    const float* W1  = (const float*)d_in[5];
    const float* b1  = (const float*)d_in[6];
    const float* W2  = (const float*)d_in[7];
    const float* b2  = (const float*)d_in[8];
    float* ws  = (float*)d_ws;
    float* out = (float*)d_out;

    fused_k12<<<3584, 256, 0, stream>>>(d, si, sj, mi, mj, W1, b1, W2, ws);
    k3_final<<<BB, 64, 0, stream>>>(ws, b2, out);
}

// Round 14
// 53.234 us; speedup vs baseline: 1.4913x; 1.2609x over previous
//
#include <hip/hip_runtime.h>
#include <math.h>

#define BB 256
#define NN 1024
#define DD 128
#define NCHUNK 4
#define ROWS (NN / NCHUNK)   // 256

// workspace layout (in floats)
#define PA_OFF   0
#define PCI_OFF  (NCHUNK*BB*DD)            // 131072
#define PCJ_OFF  (2*NCHUNK*BB*DD)          // 262144
#define PCNT_OFF (3*NCHUNK*BB*DD)          // 393216
#define U_OFF    (PCNT_OFF + NCHUNK*BB)    // 394240
#define V_OFF    (U_OFF + BB*DD)           // 427008
// total = 459776 floats = 1.84 MB

typedef _Float16 f16x8 __attribute__((ext_vector_type(8)));
typedef float    f32x4 __attribute__((ext_vector_type(4)));

// ---------------------------------------------------------------------------
// Kernel 1 (r9-exact): SPARSE masked streaming reductions, one array/block.
//   role 0: P_A = sum_n (mi-mj)*d ; 1: P_Ci = sum_n mi*si ; 2: P_Cj = mj*sj
// Zero-weight rows (~50%) compacted away, never loaded.
// grid = (NCHUNK, BB, 3), block = 256 (32 lanes x 8 row-groups).
// ---------------------------------------------------------------------------
__global__ __launch_bounds__(256) void k1_sparse(
    const float* __restrict__ d, const float* __restrict__ si,
    const float* __restrict__ sj, const void* __restrict__ miv,
    const void* __restrict__ mjv, float* __restrict__ ws)
{
    const int chunk = blockIdx.x;
    const int b     = blockIdx.y;
    const int role  = blockIdx.z;
    const int t     = threadIdx.x;
    const int lane  = t & 31;   // float4 column group: cols lane*4 .. +3
    const int rg    = t >> 5;   // row group 0..7
    const int wid   = t >> 6;   // wave 0..3
    const int l64   = t & 63;

    // ---- mask dtype auto-detect (bool bytes vs int32) ----
    __shared__ int s_mode;
    if (t == 0) s_mode = 0;
    __syncthreads();
    {
        const unsigned int* a = (const unsigned int*)miv;
        const unsigned int* c = (const unsigned int*)mjv;
        if ((a[t] | c[t]) > 1u) s_mode = 1;  // bytes of 0/1 packed in a word
    }
    __syncthreads();
    const bool bytes_mode = (s_mode != 0);

    // ---- stage weights, compute cnt (role 0), compact nonzero rows ----
    __shared__ float s_wc[ROWS];     // compacted weights
    __shared__ short s_idx[ROWS];    // compacted row indices (0..255)
    __shared__ int   s_wcnt[4];      // per-wave keep counts
    __shared__ int   s_woff[5];      // exclusive scan + total
    __shared__ int   s_cnt4[4];      // per-wave (sum mi - sum mj)

    const int    n0      = chunk * ROWS;
    const size_t rowbase = (size_t)b * NN;

    float w;
    {
        const size_t m = rowbase + (size_t)(n0 + t);
        float fi, fj;
        if (bytes_mode) {
            fi = (float)((const unsigned char*)miv)[m];
            fj = (float)((const unsigned char*)mjv)[m];
        } else {
            fi = (float)((const int*)miv)[m];
            fj = (float)((const int*)mjv)[m];
        }
        w = (role == 0) ? (fi - fj) : ((role == 1) ? fi : fj);
        if (role == 0) {
            const unsigned long long bi = __ballot(fi != 0.f);
            const unsigned long long bj = __ballot(fj != 0.f);
            if (l64 == 0) s_cnt4[wid] = __popcll(bi) - __popcll(bj);
        }
    }
    const bool keep = (w != 0.f);
    const unsigned long long ball = __ballot(keep);
    const int prefix = __popcll(ball & ((1ull << l64) - 1ull));
    if (l64 == 0) s_wcnt[wid] = __popcll(ball);
    __syncthreads();
    if (t == 0) {
        int a0 = 0;
        #pragma unroll
        for (int ww = 0; ww < 4; ++ww) { s_woff[ww] = a0; a0 += s_wcnt[ww]; }
        s_woff[4] = a0;
        if (role == 0)
            ws[PCNT_OFF + chunk * BB + b] =
                (float)(s_cnt4[0] + s_cnt4[1] + s_cnt4[2] + s_cnt4[3]);
    }
    __syncthreads();
    const int K    = s_woff[4];
    const int Kpad = (K + 31) & ~31;
    if (keep) {
        const int pos = s_woff[wid] + prefix;
        s_idx[pos] = (short)t;
        s_wc[pos]  = w;
    }
    for (int p = K + t; p < Kpad; p += 256) { s_idx[p] = 0; s_wc[p] = 0.f; }
    __syncthreads();

    const float* src = (role == 0) ? d : ((role == 1) ? si : sj);
    const size_t cbase = (rowbase + (size_t)n0) * (size_t)DD
                       + (size_t)lane * 4;

    float acc[4] = {0.f, 0.f, 0.f, 0.f};

    for (int i = 0; i < Kpad; i += 32) {
        int   r[4];
        float wv[4];
        #pragma unroll
        for (int u = 0; u < 4; ++u) {
            const int p = i + u * 8 + rg;
            r[u]  = s_idx[p];      // broadcast within row-group
            wv[u] = s_wc[p];
        }
        float4 v[4];
        #pragma unroll
        for (int u = 0; u < 4; ++u)
            v[u] = *(const float4*)(src + cbase + (size_t)r[u] * DD);
        #pragma unroll
        for (int u = 0; u < 4; ++u) {
            acc[0] = fmaf(wv[u], v[u].x, acc[0]);
            acc[1] = fmaf(wv[u], v[u].y, acc[1]);
            acc[2] = fmaf(wv[u], v[u].z, acc[2]);
            acc[3] = fmaf(wv[u], v[u].w, acc[3]);
        }
    }

    // ---- reduce the 8 row-groups (t strides of 32); [5] breaks bank stride
    __shared__ float red[256][5];
    #pragma unroll
    for (int i = 0; i < 4; ++i) red[t][i] = acc[i];
    __syncthreads();
    if (t < 128) {
        #pragma unroll
        for (int i = 0; i < 4; ++i) red[t][i] += red[t + 128][i];
    }
    __syncthreads();
    if (t < 64) {
        #pragma unroll
        for (int i = 0; i < 4; ++i) red[t][i] += red[t + 64][i];
    }
    __syncthreads();
    if (t < 32) {
        #pragma unroll
        for (int i = 0; i < 4; ++i) red[t][i] += red[t + 32][i];
        const size_t poff = ((role == 0) ? PA_OFF : ((role == 1) ? PCI_OFF
                                                                 : PCJ_OFF))
                          + ((size_t)chunk * BB + b) * DD;
        float* P = ws + poff;
        #pragma unroll
        for (int i = 0; i < 4; ++i) P[t * 4 + i] = red[t][i];
    }
}

// ---------------------------------------------------------------------------
// Kernel 2 (v5, MFMA f16): M = relu(dm @ W1 + b1); u = M_p·w2a, v = M_p·w2b.
// One block = one p-column group (128 q = all c of one p) x 64 b.
//   grid (128 p, 4 bg), block 256 = 4 waves; wave w owns b-rows [16w,16w+16).
//   A: dm[64b x 128k] f32->f16 LDS [b][k] (pad 136).
//   B: W1[:, p*128 + c] f32->f16 LDS TRANSPOSED [c][k] (pad 136) so B-frags
//      are contiguous ds_read_b128.
//   8 mfma_f32_16x16x32_f16 per wave per k-step, 4 k-steps (K=128).
//   Epilogue in-register: relu+bias, contract c with w2a/w2b, shfl_xor
//   reduce over the 16-lane col group, direct store to U/V.
// f16 precision: score err ~0.013 pre-sigmoid -> ~<=0.01 out, threshold 0.02.
// ---------------------------------------------------------------------------
__global__ __launch_bounds__(256) void k2_mfma(
    const float* __restrict__ d, const float* __restrict__ W1,
    const float* __restrict__ b1, const float* __restrict__ W2,
    float* __restrict__ ws)
{
    const int p    = blockIdx.x;      // 0..127
    const int b0   = blockIdx.y * 64; // 0,64,128,192
    const int t    = threadIdx.x;
    const int wid  = t >> 6;          // wave 0..3
    const int lane = t & 63;
    const int lcol = lane & 15;       // col within 16x16 tile
    const int lrow = lane >> 4;       // k-chunk selector / row-quad selector

    __shared__ _Float16 As[64][136];   // [b][k]
    __shared__ _Float16 Bs[128][136];  // [c][k] (W1 transposed)

    // ---- stage A: d[b0+bb][0][k], f32 -> f16 ----
    for (int idx = t; idx < 64 * 32; idx += 256) {
        const int bb = idx >> 5;
        const int k4 = (idx & 31) * 4;
        const float4 v = *(const float4*)(d + (size_t)(b0 + bb) * (NN * DD) + k4);
        As[bb][k4 + 0] = (_Float16)v.x;
        As[bb][k4 + 1] = (_Float16)v.y;
        As[bb][k4 + 2] = (_Float16)v.z;
        As[bb][k4 + 3] = (_Float16)v.w;
    }
    // ---- stage B transposed: W1[k][p*128+c] -> Bs[c][k], f32 -> f16 ----
    for (int idx = t; idx < 128 * 32; idx += 256) {
        const int k  = idx >> 5;
        const int c4 = (idx & 31) * 4;
        const float4 v =
            *(const float4*)(W1 + (size_t)k * 16384 + p * 128 + c4);
        Bs[c4 + 0][k] = (_Float16)v.x;
        Bs[c4 + 1][k] = (_Float16)v.y;
        Bs[c4 + 2][k] = (_Float16)v.z;
        Bs[c4 + 3][k] = (_Float16)v.w;
    }
    __syncthreads();

    // ---- MFMA main loop: C[64b x 128q], wave tile 16b x 128q ----
    f32x4 acc[8];
    #pragma unroll
    for (int n = 0; n < 8; ++n) acc[n] = (f32x4){0.f, 0.f, 0.f, 0.f};

    #pragma unroll
    for (int ks = 0; ks < 4; ++ks) {
        const int k0 = ks * 32;
        // A-frag: row = wid*16 + lcol, k = k0 + lrow*8 + i  (contiguous 16B)
        const f16x8 afrag = *(const f16x8*)&As[wid * 16 + lcol][k0 + lrow * 8];
        #pragma unroll
        for (int n = 0; n < 8; ++n) {
            // B-frag: col = n*16 + lcol, k = k0 + lrow*8 + i
            const f16x8 bfrag =
                *(const f16x8*)&Bs[n * 16 + lcol][k0 + lrow * 8];
            acc[n] = __builtin_amdgcn_mfma_f32_16x16x32_f16(
                afrag, bfrag, acc[n], 0, 0, 0);
        }
    }

    // ---- epilogue: relu + bias, contract over c, reduce 16-lane groups ----
    // lane holds rows r = wid*16 + lrow*4 + reg (reg 0..3), col c = n*16+lcol
    float ua[4] = {0.f, 0.f, 0.f, 0.f};
    float va[4] = {0.f, 0.f, 0.f, 0.f};
    #pragma unroll
    for (int n = 0; n < 8; ++n) {
        const int c = n * 16 + lcol;
        const float bias = b1[p * 128 + c];
        const float w2a  = W2[c];
        const float w2b  = W2[128 + c];
        #pragma unroll
        for (int reg = 0; reg < 4; ++reg) {
            const float g = fmaxf(acc[n][reg] + bias, 0.f);
            ua[reg] = fmaf(g, w2a, ua[reg]);
            va[reg] = fmaf(g, w2b, va[reg]);
        }
    }
    // reduce across the 16 cols (lanes differing in bits 0..3 share rows)
    #pragma unroll
    for (int off = 8; off > 0; off >>= 1) {
        #pragma unroll
        for (int reg = 0; reg < 4; ++reg) {
            ua[reg] += __shfl_xor(ua[reg], off, 64);
            va[reg] += __shfl_xor(va[reg], off, 64);
        }
    }
    if (lcol == 0) {
        #pragma unroll
        for (int reg = 0; reg < 4; ++reg) {
            const int b = b0 + wid * 16 + lrow * 4 + reg;
            ws[U_OFF + (size_t)b * DD + p] = ua[reg];
            ws[V_OFF + (size_t)b * DD + p] = va[reg];
        }
    }
}

// ---------------------------------------------------------------------------
// Kernel 3: per-batch score assembly + sigmoid.
//   out[b] = sigmoid( Adiff·u + (Ci-Cj)·v + b2*cntdiff )
// grid = 256, block = 64 (one wave per batch).
// ---------------------------------------------------------------------------
__global__ __launch_bounds__(64) void k3_final(
    const float* __restrict__ ws, const float* __restrict__ b2p,
    float* __restrict__ out)
{
    const int b = blockIdx.x;
    const int l = threadIdx.x;

    float s = 0.f;
    #pragma unroll
    for (int rep = 0; rep < 2; ++rep) {
        const int k = l + rep * 64;
        float A = 0.f, Ci = 0.f, Cj = 0.f;
        #pragma unroll
        for (int c = 0; c < NCHUNK; ++c) {
            A  += ws[PA_OFF  + ((size_t)c * BB + b) * DD + k];
            Ci += ws[PCI_OFF + ((size_t)c * BB + b) * DD + k];
            Cj += ws[PCJ_OFF + ((size_t)c * BB + b) * DD + k];
        }
        s += A * ws[U_OFF + (size_t)b * DD + k]
           + (Ci - Cj) * ws[V_OFF + (size_t)b * DD + k];
    }
    #pragma unroll
    for (int off = 32; off > 0; off >>= 1) s += __shfl_down(s, off, 64);

    if (l == 0) {
        float cnt = 0.f;
        #pragma unroll
        for (int c = 0; c < NCHUNK; ++c) cnt += ws[PCNT_OFF + c * BB + b];
        const float score = s + b2p[0] * cnt;   // SCALING_FACTOR == 1.0
        out[b] = 1.f / (1.f + expf(-score));
    }
}

extern "C" void kernel_launch(void* const* d_in, const int* in_sizes, int n_in,
                              void* d_out, int out_size, void* d_ws, size_t ws_size,
                              hipStream_t stream)
{
    const float* d   = (const float*)d_in[0];
    const float* si  = (const float*)d_in[1];
    const float* sj  = (const float*)d_in[2];
    const void*  mi  = d_in[3];
    const void*  mj  = d_in[4];
    const float* W1  = (const float*)d_in[5];
    const float* b1  = (const float*)d_in[6];
    const float* W2  = (const float*)d_in[7];
    const float* b2  = (const float*)d_in[8];
    float* ws  = (float*)d_ws;
    float* out = (float*)d_out;

    dim3 g1(NCHUNK, BB, 3);
    k1_sparse<<<g1, 256, 0, stream>>>(d, si, sj, mi, mj, ws);
    dim3 g2(128, 4);
    k2_mfma<<<g2, 256, 0, stream>>>(d, W1, b1, W2, ws);
    k3_final<<<BB, 64, 0, stream>>>(ws, b2, out);
}

// Round 15
// 44.199 us; speedup vs baseline: 1.7961x; 1.2044x over previous
//
#include <hip/hip_runtime.h>
#include <math.h>

#define BB 256
#define NN 1024
#define DD 128
#define NCHUNK 4
#define ROWS (NN / NCHUNK)   // 256

// workspace layout (in floats)
#define PA_OFF   0
#define PCI_OFF  (NCHUNK*BB*DD)            // 131072
#define PCJ_OFF  (2*NCHUNK*BB*DD)          // 262144
#define PCNT_OFF (3*NCHUNK*BB*DD)          // 393216
#define U0_OFF   (PCNT_OFF + NCHUNK*BB)    // 394240
#define V0_OFF   (U0_OFF + BB*DD)          // 427008
#define U1_OFF   (V0_OFF + BB*DD)          // 459776
#define V1_OFF   (U1_OFF + BB*DD)          // 492544
// total = 525312 floats = 2.10 MB

typedef _Float16 f16x8 __attribute__((ext_vector_type(8)));
typedef float    f32x4 __attribute__((ext_vector_type(4)));

// ---------------------------------------------------------------------------
// Fused kernel: 4096 blocks = 3072 k1-role + 1024 k2-role ((idx&3)==1 -> k2).
// k1 is HBM-bound (VALUBusy 4%, MfmaUtil 0); k2 is MFMA + L2 staging ->
// rides under k1's memory time (m114: separate pipes co-schedule max-not-sum).
//
// k1 role (r9-exact body, aliased LDS): sparse masked streaming reductions.
//   role 0: P_A = sum_n (mi-mj)*d ; 1: P_Ci = sum_n mi*si ; 2: P_Cj = mj*sj
// k2 role: 64b x 64c MFMA tile of M = relu(dm@W1+b1), fused w2 contraction.
//   Bs (W1 c-half, f16, transposed [c][k]) = 17.4 KB LDS -- the ONLY LDS,
//   so per-block LDS stays 17.4 KB and k1-role occupancy is uncapped.
//   A-frags: per-lane direct global loads from d[:,0,:] (L2-resident) + cvt.
//   c-half partials go to U0/V0 (chalf=0) or U1/V1 (chalf=1); k3 sums.
// ---------------------------------------------------------------------------
__global__ __launch_bounds__(256) void fused_k12(
    const float* __restrict__ d, const float* __restrict__ si,
    const float* __restrict__ sj, const void* __restrict__ miv,
    const void* __restrict__ mjv, const float* __restrict__ W1,
    const float* __restrict__ b1, const float* __restrict__ W2,
    float* __restrict__ ws)
{
    const int idx = blockIdx.x;
    const int t   = threadIdx.x;

    // one shared buffer, aliased per role (prevents LDS sum-blowup)
    __shared__ __align__(16) char smem[17408];

    if ((idx & 3) == 1) {
        // =================== k2 role (MFMA) ===================
        const int k2id  = idx >> 2;        // 0..1023
        const int ctile = k2id & 255;      // 256 c-tiles = 128 p x 2 halves
        const int bg    = k2id >> 8;       // 0..3
        const int p     = ctile >> 1;
        const int chalf = ctile & 1;
        const int c0b   = chalf * 64;
        const int b0    = bg * 64;
        const int wid   = t >> 6;          // wave 0..3
        const int lane  = t & 63;
        const int lcol  = lane & 15;
        const int lrow  = lane >> 4;

        _Float16 (*Bs)[136] = (_Float16(*)[136])smem;   // [c][k] 17408 B

        // stage B transposed: W1[k][p*128 + c0b + c] -> Bs[c][k], f32->f16
        for (int s = t; s < 128 * 16; s += 256) {
            const int k  = s >> 4;
            const int c4 = (s & 15) * 4;
            const float4 v =
                *(const float4*)(W1 + (size_t)k * 16384 + p * 128 + c0b + c4);
            Bs[c4 + 0][k] = (_Float16)v.x;
            Bs[c4 + 1][k] = (_Float16)v.y;
            Bs[c4 + 2][k] = (_Float16)v.z;
            Bs[c4 + 3][k] = (_Float16)v.w;
        }
        __syncthreads();

        // A rows direct from global (d[:,0,:] is 128 KB, L2-resident)
        const int brow = b0 + wid * 16 + lcol;
        const float* drow = d + (size_t)brow * (NN * DD);

        f32x4 acc[4];
        #pragma unroll
        for (int n = 0; n < 4; ++n) acc[n] = (f32x4){0.f, 0.f, 0.f, 0.f};

        #pragma unroll
        for (int ks = 0; ks < 4; ++ks) {
            const int kf = ks * 32 + lrow * 8;
            const float4 a0 = *(const float4*)(drow + kf);
            const float4 a1 = *(const float4*)(drow + kf + 4);
            f16x8 afrag;
            afrag[0] = (_Float16)a0.x; afrag[1] = (_Float16)a0.y;
            afrag[2] = (_Float16)a0.z; afrag[3] = (_Float16)a0.w;
            afrag[4] = (_Float16)a1.x; afrag[5] = (_Float16)a1.y;
            afrag[6] = (_Float16)a1.z; afrag[7] = (_Float16)a1.w;
            #pragma unroll
            for (int n = 0; n < 4; ++n) {
                const f16x8 bfrag = *(const f16x8*)&Bs[n * 16 + lcol][kf];
                acc[n] = __builtin_amdgcn_mfma_f32_16x16x32_f16(
                    afrag, bfrag, acc[n], 0, 0, 0);
            }
        }

        // epilogue: relu+bias, contract c with w2a/w2b (verified C/D layout:
        // col=lane&15, row=(lane>>4)*4+reg)
        float ua[4] = {0.f, 0.f, 0.f, 0.f};
        float va[4] = {0.f, 0.f, 0.f, 0.f};
        #pragma unroll
        for (int n = 0; n < 4; ++n) {
            const int c = c0b + n * 16 + lcol;
            const float bias = b1[p * 128 + c];
            const float w2a  = W2[c];
            const float w2b  = W2[128 + c];
            #pragma unroll
            for (int reg = 0; reg < 4; ++reg) {
                const float g = fmaxf(acc[n][reg] + bias, 0.f);
                ua[reg] = fmaf(g, w2a, ua[reg]);
                va[reg] = fmaf(g, w2b, va[reg]);
            }
        }
        #pragma unroll
        for (int off = 8; off > 0; off >>= 1) {
            #pragma unroll
            for (int reg = 0; reg < 4; ++reg) {
                ua[reg] += __shfl_xor(ua[reg], off, 64);
                va[reg] += __shfl_xor(va[reg], off, 64);
            }
        }
        if (lcol == 0) {
            const size_t uo = chalf ? U1_OFF : U0_OFF;
            const size_t vo = chalf ? V1_OFF : V0_OFF;
            #pragma unroll
            for (int reg = 0; reg < 4; ++reg) {
                const int b = b0 + wid * 16 + lrow * 4 + reg;
                ws[uo + (size_t)b * DD + p] = ua[reg];
                ws[vo + (size_t)b * DD + p] = va[reg];
            }
        }
        return;
    }

    // =================== k1 role (r9-exact body, aliased LDS) ===============
    const int q4 = idx >> 2, r4 = idx & 3;
    const int k1id  = q4 * 3 + (r4 == 0 ? 0 : r4 - 1);   // 0..3071
    const int chunk = k1id & 3;
    const int b     = (k1id >> 2) & 255;
    const int role  = k1id >> 10;
    const int lane  = t & 31;   // float4 column group: cols lane*4 .. +3
    const int rg    = t >> 5;   // row group 0..7
    const int wid   = t >> 6;   // wave 0..3
    const int l64   = t & 63;

    // aliased LDS layout inside smem (total 6720 B <= 17408)
    float* s_wc   = (float*)smem;              // [256]  @0
    short* s_idx  = (short*)(smem + 1024);     // [256]  @1024
    int*   s_wcnt = (int*)(smem + 1536);       // [4]
    int*   s_woff = (int*)(smem + 1552);       // [5]
    int*   s_cnt4 = (int*)(smem + 1572);       // [4]
    int*   s_mode = (int*)(smem + 1588);       // [1]
    float (*red)[5] = (float(*)[5])(smem + 1600);  // [256][5]

    // ---- mask dtype auto-detect (bool bytes vs int32) ----
    if (t == 0) *s_mode = 0;
    __syncthreads();
    {
        const unsigned int* a = (const unsigned int*)miv;
        const unsigned int* c = (const unsigned int*)mjv;
        if ((a[t] | c[t]) > 1u) *s_mode = 1;  // bytes of 0/1 packed in a word
    }
    __syncthreads();
    const bool bytes_mode = (*s_mode != 0);

    const int    n0      = chunk * ROWS;
    const size_t rowbase = (size_t)b * NN;

    float w;
    {
        const size_t m = rowbase + (size_t)(n0 + t);
        float fi, fj;
        if (bytes_mode) {
            fi = (float)((const unsigned char*)miv)[m];
            fj = (float)((const unsigned char*)mjv)[m];
        } else {
            fi = (float)((const int*)miv)[m];
            fj = (float)((const int*)mjv)[m];
        }
        w = (role == 0) ? (fi - fj) : ((role == 1) ? fi : fj);
        if (role == 0) {
            const unsigned long long bi = __ballot(fi != 0.f);
            const unsigned long long bj = __ballot(fj != 0.f);
            if (l64 == 0) s_cnt4[wid] = __popcll(bi) - __popcll(bj);
        }
    }
    const bool keep = (w != 0.f);
    const unsigned long long ball = __ballot(keep);
    const int prefix = __popcll(ball & ((1ull << l64) - 1ull));
    if (l64 == 0) s_wcnt[wid] = __popcll(ball);
    __syncthreads();
    if (t == 0) {
        int a0 = 0;
        #pragma unroll
        for (int ww = 0; ww < 4; ++ww) { s_woff[ww] = a0; a0 += s_wcnt[ww]; }
        s_woff[4] = a0;
        if (role == 0)
            ws[PCNT_OFF + chunk * BB + b] =
                (float)(s_cnt4[0] + s_cnt4[1] + s_cnt4[2] + s_cnt4[3]);
    }
    __syncthreads();
    const int K    = s_woff[4];
    const int Kpad = (K + 31) & ~31;
    if (keep) {
        const int pos = s_woff[wid] + prefix;
        s_idx[pos] = (short)t;
        s_wc[pos]  = w;
    }
    for (int p = K + t; p < Kpad; p += 256) { s_idx[p] = 0; s_wc[p] = 0.f; }
    __syncthreads();

    const float* src = (role == 0) ? d : ((role == 1) ? si : sj);
    const size_t cbase = (rowbase + (size_t)n0) * (size_t)DD
                       + (size_t)lane * 4;

    float acc[4] = {0.f, 0.f, 0.f, 0.f};

    for (int i = 0; i < Kpad; i += 32) {
        int   r[4];
        float wv[4];
        #pragma unroll
        for (int u = 0; u < 4; ++u) {
            const int p = i + u * 8 + rg;
            r[u]  = s_idx[p];      // broadcast within row-group
            wv[u] = s_wc[p];
        }
        float4 v[4];
        #pragma unroll
        for (int u = 0; u < 4; ++u)
            v[u] = *(const float4*)(src + cbase + (size_t)r[u] * DD);
        #pragma unroll
        for (int u = 0; u < 4; ++u) {
            acc[0] = fmaf(wv[u], v[u].x, acc[0]);
            acc[1] = fmaf(wv[u], v[u].y, acc[1]);
            acc[2] = fmaf(wv[u], v[u].z, acc[2]);
            acc[3] = fmaf(wv[u], v[u].w, acc[3]);
        }
    }

    // ---- reduce the 8 row-groups (t strides of 32); [5] breaks bank stride
    #pragma unroll
    for (int i = 0; i < 4; ++i) red[t][i] = acc[i];
    __syncthreads();
    if (t < 128) {
        #pragma unroll
        for (int i = 0; i < 4; ++i) red[t][i] += red[t + 128][i];
    }
    __syncthreads();
    if (t < 64) {
        #pragma unroll
        for (int i = 0; i < 4; ++i) red[t][i] += red[t + 64][i];
    }
    __syncthreads();
    if (t < 32) {
        #pragma unroll
        for (int i = 0; i < 4; ++i) red[t][i] += red[t + 32][i];
        const size_t poff = ((role == 0) ? PA_OFF : ((role == 1) ? PCI_OFF
                                                                 : PCJ_OFF))
                          + ((size_t)chunk * BB + b) * DD;
        float* P = ws + poff;
        #pragma unroll
        for (int i = 0; i < 4; ++i) P[t * 4 + i] = red[t][i];
    }
}

// ---------------------------------------------------------------------------
// Kernel 3: per-batch score assembly + sigmoid.
//   out[b] = sigmoid( Adiff·(u0+u1) + (Ci-Cj)·(v0+v1) + b2*cntdiff )
// grid = 256, block = 64 (one wave per batch).
// ---------------------------------------------------------------------------
__global__ __launch_bounds__(64) void k3_final(
    const float* __restrict__ ws, const float* __restrict__ b2p,
    float* __restrict__ out)
{
    const int b = blockIdx.x;
    const int l = threadIdx.x;

    float s = 0.f;
    #pragma unroll
    for (int rep = 0; rep < 2; ++rep) {
        const int k = l + rep * 64;
        float A = 0.f, Ci = 0.f, Cj = 0.f;
        #pragma unroll
        for (int c = 0; c < NCHUNK; ++c) {
            A  += ws[PA_OFF  + ((size_t)c * BB + b) * DD + k];
            Ci += ws[PCI_OFF + ((size_t)c * BB + b) * DD + k];
            Cj += ws[PCJ_OFF + ((size_t)c * BB + b) * DD + k];
        }
        const float u = ws[U0_OFF + (size_t)b * DD + k]
                      + ws[U1_OFF + (size_t)b * DD + k];
        const float v = ws[V0_OFF + (size_t)b * DD + k]
                      + ws[V1_OFF + (size_t)b * DD + k];
        s += A * u + (Ci - Cj) * v;
    }
    #pragma unroll
    for (int off = 32; off > 0; off >>= 1) s += __shfl_down(s, off, 64);

    if (l == 0) {
        float cnt = 0.f;
        #pragma unroll
        for (int c = 0; c < NCHUNK; ++c) cnt += ws[PCNT_OFF + c * BB + b];
        const float score = s + b2p[0] * cnt;   // SCALING_FACTOR == 1.0
        out[b] = 1.f / (1.f + expf(-score));
    }
}

extern "C" void kernel_launch(void* const* d_in, const int* in_sizes, int n_in,
                              void* d_out, int out_size, void* d_ws, size_t ws_size,
                              hipStream_t stream)
{
    const float* d   = (const float*)d_in[0];
    const float* si  = (const float*)d_in[1];
    const float* sj  = (const float*)d_in[2];
    const void*  mi  = d_in[3];
    const void*  mj  = d_in[4];
    const float* W1  = (const float*)d_in[5];
    const float* b1  = (const float*)d_in[6];
    const float* W2  = (const float*)d_in[7];
    const float* b2  = (const float*)d_in[8];
    float* ws  = (float*)d_ws;
    float* out = (float*)d_out;

    fused_k12<<<4096, 256, 0, stream>>>(d, si, sj, mi, mj, W1, b1, W2, ws);
    k3_final<<<BB, 64, 0, stream>>>(ws, b2, out);
}